// Round 2
// baseline (292.457 us; speedup 1.0000x reference)
//
#include <hip/hip_runtime.h>
#include <hip/hip_bf16.h>
#include <math.h>

#define SCALE 0.1767766952966369f        // 1/sqrt(32)
#define LN_EPS 1e-5f

typedef short bf16x8 __attribute__((ext_vector_type(8)));
typedef float f32x4 __attribute__((ext_vector_type(4)));

__device__ __forceinline__ unsigned short f2bf(float f) {
    __hip_bfloat16 h = __float2bfloat16(f);
    return *reinterpret_cast<unsigned short*>(&h);
}
__device__ __forceinline__ float bf2f(unsigned short u) {
    union { unsigned int u32; float f; } c;
    c.u32 = ((unsigned int)u) << 16;
    return c.f;
}
__device__ __forceinline__ unsigned int pack2(float a, float b) {
    return (unsigned int)f2bf(a) | ((unsigned int)f2bf(b) << 16);
}

// ---------------------------------------------------------------------------
// Kernel 0: weight convert+transpose to bf16. WT[m][col][k] m=q,k,v,g,o.
// Block 20: WbT[16][128] zero-padded (rows 4..15 = 0).  (round-6 proven)
// ---------------------------------------------------------------------------
__global__ __launch_bounds__(256)
void k_prep(const float* __restrict__ Wq, const float* __restrict__ Wk,
            const float* __restrict__ Wv, const float* __restrict__ Wg,
            const float* __restrict__ Wo, const float* __restrict__ Wb,
            unsigned short* __restrict__ WT, unsigned short* __restrict__ WbT)
{
    if (blockIdx.x == 20) {
        int t = threadIdx.x;
        int row = t >> 4, k0 = (t & 15) * 8;
        unsigned int u[4];
        #pragma unroll
        for (int e = 0; e < 4; ++e) {
            float a = 0.f, b = 0.f;
            if (row < 4) {
                a = Wb[(k0 + 2*e    )*4 + row];
                b = Wb[(k0 + 2*e + 1)*4 + row];
            }
            u[e] = pack2(a, b);
        }
        *(uint4*)(WbT + row*128 + k0) = make_uint4(u[0], u[1], u[2], u[3]);
        return;
    }
    int idx = blockIdx.x * 256 + threadIdx.x;     // < 5120
    int m   = idx >> 10;
    int col = (idx >> 3) & 127;
    int k0  = (idx & 7) * 16;
    const float* W = (m==0) ? Wq : (m==1) ? Wk : (m==2) ? Wv : (m==3) ? Wg : Wo;
    unsigned int u[8];
    #pragma unroll
    for (int e = 0; e < 8; ++e) {
        float a = W[(k0 + 2*e    )*128 + col];
        float b = W[(k0 + 2*e + 1)*128 + col];
        u[e] = pack2(a, b);
    }
    uint4* dst = (uint4*)(WT + m*16384 + col*128 + k0);
    dst[0] = make_uint4(u[0], u[1], u[2], u[3]);
    dst[1] = make_uint4(u[4], u[5], u[6], u[7]);
}

// ---------------------------------------------------------------------------
// Kernel 1: LN + projections, GEMM-style with W staged in LDS.
// grid 1024: j = blk>>2, i0base = (blk&3)*64. 256 thr, wave w owns one
// 16-row tile ti = i0base + w*16.
// BIAS layout: round-0 proven [n][i>>2][k][i&3] (float4-per-(i>>2,k)).
// ---------------------------------------------------------------------------
__global__ __launch_bounds__(256)
void k_ln_proj(const float* __restrict__ x, const float* __restrict__ gamma,
               const float* __restrict__ beta,
               const unsigned short* __restrict__ WT,
               const unsigned short* __restrict__ WbT,
               const float* __restrict__ bg,
               unsigned short* __restrict__ Q, unsigned short* __restrict__ K,
               unsigned short* __restrict__ VT, unsigned short* __restrict__ G,
               float* __restrict__ BIAS)
{
    __shared__ unsigned short Wbuf[64*136];     // staged W half  (17408 B)
    __shared__ unsigned short stg[4][2176];     // per-wave epilogue staging

    const int t    = threadIdx.x;
    const int lane = t & 63, w = t >> 6;
    const int l15  = lane & 15, quad = lane >> 4;
    const int j    = blockIdx.x >> 2;
    const int ti   = (blockIdx.x & 3) * 64 + w*16;   // this wave's 16 rows
    unsigned short* sw = stg[w];

    // ---- LayerNorm in registers (rows ti+l15, column j) ----
    float v[32];
    {
        const float* xr = x + ((size_t)(ti + l15)*256 + j)*128;
        float sum = 0.f, ssq = 0.f;
        #pragma unroll
        for (int kt = 0; kt < 4; ++kt) {
            float4 f0 = *(const float4*)(xr + kt*32 + quad*8);
            float4 f1 = *(const float4*)(xr + kt*32 + quad*8 + 4);
            v[kt*8+0]=f0.x; v[kt*8+1]=f0.y; v[kt*8+2]=f0.z; v[kt*8+3]=f0.w;
            v[kt*8+4]=f1.x; v[kt*8+5]=f1.y; v[kt*8+6]=f1.z; v[kt*8+7]=f1.w;
            sum += f0.x+f0.y+f0.z+f0.w + f1.x+f1.y+f1.z+f1.w;
            ssq += f0.x*f0.x+f0.y*f0.y+f0.z*f0.z+f0.w*f0.w
                 + f1.x*f1.x+f1.y*f1.y+f1.z*f1.z+f1.w*f1.w;
        }
        sum += __shfl_xor(sum, 16); ssq += __shfl_xor(ssq, 16);
        sum += __shfl_xor(sum, 32); ssq += __shfl_xor(ssq, 32);
        float mu  = sum * (1.f/128.f);
        float var = ssq * (1.f/128.f) - mu*mu;
        float rs  = rsqrtf(var + LN_EPS);
        #pragma unroll
        for (int kt = 0; kt < 4; ++kt)
            #pragma unroll
            for (int e = 0; e < 8; ++e) {
                int c = kt*32 + quad*8 + e;
                v[kt*8+e] = (v[kt*8+e]-mu)*rs*gamma[c] + beta[c];
            }
    }
    bf16x8 afrag[4];
    #pragma unroll
    for (int kt = 0; kt < 4; ++kt)
        #pragma unroll
        for (int e = 0; e < 8; ++e)
            afrag[kt][e] = (short)f2bf(v[kt*8+e]);

    // ---- bias via MFMA with zero-padded WbT (round-0 layout) ----
    {
        f32x4 bacc = (f32x4){0.f,0.f,0.f,0.f};
        #pragma unroll
        for (int kt = 0; kt < 4; ++kt) {
            bf16x8 b = *(const bf16x8*)(WbT + (size_t)l15*128 + kt*32 + quad*8);
            bacc = __builtin_amdgcn_mfma_f32_16x16x32_bf16(afrag[kt], b, bacc, 0, 0, 0);
        }
        if (l15 < 4) {
            #pragma unroll
            for (int reg = 0; reg < 4; ++reg)
                BIAS[l15*65536 + ((ti >> 2) + quad)*1024 + j*4 + reg] = bacc[reg];
        }
    }

    // ---- 4 projection matrices, W through LDS in 64-col halves ----
    #pragma unroll 1
    for (int mm = 0; mm < 4; ++mm) {
        f32x4 acc[8];
        #pragma unroll
        for (int nt = 0; nt < 8; ++nt) acc[nt] = (f32x4){0.f,0.f,0.f,0.f};

        #pragma unroll 1
        for (int half = 0; half < 2; ++half) {
            __syncthreads();   // Wbuf free of previous phase's readers
            #pragma unroll
            for (int r = 0; r < 4; ++r) {
                int idx = r*256 + t;               // 1024 8-short chunks
                int col = idx >> 4, kc = idx & 15;
                *(uint4*)&Wbuf[col*136 + kc*8] =
                    *(const uint4*)&WT[mm*16384 + (half*64 + col)*128 + kc*8];
            }
            __syncthreads();

            #pragma unroll
            for (int kt = 0; kt < 4; ++kt) {
                #pragma unroll
                for (int nt2 = 0; nt2 < 4; ++nt2) {
                    bf16x8 b = *(const bf16x8*)&Wbuf[(nt2*16 + l15)*136 + kt*32 + quad*8];
                    if (mm == 2)
                        acc[half*4 + nt2] = __builtin_amdgcn_mfma_f32_16x16x32_bf16(
                            b, afrag[kt], acc[half*4 + nt2], 0, 0, 0);
                    else
                        acc[half*4 + nt2] = __builtin_amdgcn_mfma_f32_16x16x32_bf16(
                            afrag[kt], b, acc[half*4 + nt2], 0, 0, 0);
                }
            }
        }

        // ---- epilogue (per-wave staging, round-6 pattern) ----
        if (mm == 2) {
            // V swapped: rows = channel cc, cols = local position l15
            #pragma unroll
            for (int nt = 0; nt < 8; ++nt)
                #pragma unroll
                for (int reg = 0; reg < 4; ++reg)
                    sw[(nt*16 + quad*4 + reg)*16 + l15] = f2bf(acc[nt][reg]);
            #pragma unroll
            for (int it = 0; it < 4; ++it) {
                int idx = it*64 + lane;
                int ch = idx >> 1, c = idx & 1;
                uint4 val = *(const uint4*)&sw[ch*16 + c*8];
                int nh = ch >> 5, d = ch & 31;
                *(uint4*)&VT[(((size_t)(nh*256 + j))*32 + d)*256 + ti + c*8] = val;
            }
        } else {
            #pragma unroll
            for (int nt = 0; nt < 8; ++nt) {
                int cc = nt*16 + l15;
                float bgv = (mm == 3) ? bg[cc] : 0.f;
                #pragma unroll
                for (int reg = 0; reg < 4; ++reg) {
                    float val = acc[nt][reg];
                    if (mm == 0)      val *= SCALE;
                    else if (mm == 3) val = 1.f/(1.f + __expf(-(val + bgv)));
                    sw[(quad*4 + reg)*136 + cc] = f2bf(val);
                }
            }
            {
                int row = lane >> 2, c = lane & 3;
                unsigned short* Dst = (mm == 0) ? Q : (mm == 1) ? K : G;
                #pragma unroll
                for (int nh = 0; nh < 4; ++nh) {
                    uint4 val = *(const uint4*)&sw[row*136 + nh*32 + c*8];
                    *(uint4*)&Dst[(((size_t)(nh*256 + j))*256 + ti + row)*32 + c*8] = val;
                }
            }
        }
    }
}

// ---------------------------------------------------------------------------
// Kernel 2: attention. Round-0 structure (LDS P path, zero barriers) with
// two changes:
//  (a) two-half PV: P staged 16x128 at a time (stride 136), PV split into
//      two 4-step passes reusing the buffer. Same-wave DS ops are in-order,
//      so no hazard. LDS/block 33792 -> 17408 B => 6 blocks/CU (VGPR cap)
//      instead of 4 (LDS cap).
//  (b) ic moved to HIGH bits of blockIdx: the 4 blocks sharing one (n,j)
//      K/VT panel are b, b+1024, b+2048, b+3072 == b (mod 8) -> same XCD
//      -> panel reuse hits L2 instead of L3.
// ---------------------------------------------------------------------------
__global__ __launch_bounds__(256)
void k_attn(const unsigned short* __restrict__ Q, const unsigned short* __restrict__ K,
            const unsigned short* __restrict__ VT, const unsigned short* __restrict__ G,
            const float* __restrict__ BIAS, unsigned short* __restrict__ AO)
{
    __shared__ unsigned short P_lds[4][16*136];   // 17408 B total

    const int t    = threadIdx.x;
    const int bid  = blockIdx.x;
    const int ic   = bid >> 10;          // high bits: same (n,j) -> same XCD
    const int n    = (bid >> 8) & 3;
    const int j    = bid & 255;
    const int lane = t & 63, w = t >> 6;
    const int l15  = lane & 15, quad = lane >> 4;
    const int i0   = ic*64 + w*16;

    const size_t nb = (size_t)(n*256 + j);
    const unsigned short* qb  = Q  + nb*8192;   // [i][d], pre-scaled
    const unsigned short* kb  = K  + nb*8192;   // [k][d]
    const unsigned short* vtb = VT + nb*8192;   // [d][k]
    const unsigned short* gb  = G  + nb*8192;   // [i][d]
    const float* biasn = BIAS + n*65536;        // [i>>2][k][i&3]
    unsigned short* Pw = P_lds[w];

    // ---- QK^T: acc[kt][reg] = S[i=i0+quad*4+reg][k=kt*16+l15] ----
    bf16x8 a = *(const bf16x8*)(qb + (size_t)(i0 + l15)*32 + quad*8);
    f32x4 acc[16];
    #pragma unroll
    for (int kt = 0; kt < 16; ++kt) {
        bf16x8 b = *(const bf16x8*)(kb + (size_t)(kt*16 + l15)*32 + quad*8);
        acc[kt] = __builtin_amdgcn_mfma_f32_16x16x32_bf16(a, b, (f32x4){0.f,0.f,0.f,0.f}, 0, 0, 0);
    }

    float mx[4] = {-1e30f, -1e30f, -1e30f, -1e30f};
    #pragma unroll
    for (int kt = 0; kt < 16; ++kt) {
        float4 bv = *(const float4*)&biasn[((i0 >> 2) + quad)*1024 + (kt*16 + l15)*4];
        acc[kt][0] += bv.x; acc[kt][1] += bv.y;
        acc[kt][2] += bv.z; acc[kt][3] += bv.w;
        #pragma unroll
        for (int reg = 0; reg < 4; ++reg)
            mx[reg] = fmaxf(mx[reg], acc[kt][reg]);
    }
    #pragma unroll
    for (int m = 1; m <= 8; m <<= 1) {
        #pragma unroll
        for (int reg = 0; reg < 4; ++reg)
            mx[reg] = fmaxf(mx[reg], __shfl_xor(mx[reg], m));
    }

    float sm[4] = {0.f, 0.f, 0.f, 0.f};
    #pragma unroll
    for (int kt = 0; kt < 16; ++kt) {
        #pragma unroll
        for (int reg = 0; reg < 4; ++reg) {
            float e = __expf(acc[kt][reg] - mx[reg]);
            acc[kt][reg] = e;
            sm[reg] += e;
        }
    }
    #pragma unroll
    for (int m = 1; m <= 8; m <<= 1) {
        #pragma unroll
        for (int reg = 0; reg < 4; ++reg)
            sm[reg] += __shfl_xor(sm[reg], m);
    }
    float rinv[4];
    #pragma unroll
    for (int reg = 0; reg < 4; ++reg) rinv[reg] = 1.f / sm[reg];

    // ---- two-half PV through the halved P buffer ----
    f32x4 o[2];
    o[0] = (f32x4){0.f,0.f,0.f,0.f};
    o[1] = (f32x4){0.f,0.f,0.f,0.f};
    #pragma unroll
    for (int half = 0; half < 2; ++half) {
        #pragma unroll
        for (int ktL = 0; ktL < 8; ++ktL) {
            #pragma unroll
            for (int reg = 0; reg < 4; ++reg)
                Pw[(quad*4 + reg)*136 + ktL*16 + l15] = f2bf(acc[half*8 + ktL][reg]);
        }
        #pragma unroll
        for (int k8 = 0; k8 < 4; ++k8) {
            bf16x8 pa = *(const bf16x8*)(Pw + l15*136 + k8*32 + quad*8);
            #pragma unroll
            for (int nt = 0; nt < 2; ++nt) {
                bf16x8 vb = *(const bf16x8*)(vtb + (size_t)(nt*16 + l15)*256
                                             + (half*4 + k8)*32 + quad*8);
                o[nt] = __builtin_amdgcn_mfma_f32_16x16x32_bf16(pa, vb, o[nt], 0, 0, 0);
            }
        }
    }

    // gate + normalize -> stage -> coalesced store
    #pragma unroll
    for (int nt = 0; nt < 2; ++nt) {
        #pragma unroll
        for (int reg = 0; reg < 4; ++reg) {
            int i = i0 + quad*4 + reg;
            float g = bf2f(gb[(size_t)i*32 + nt*16 + l15]);
            float res = o[nt][reg] * rinv[reg] * g;
            Pw[(quad*4 + reg)*40 + nt*16 + l15] = f2bf(res);
        }
    }
    {
        int row = lane >> 2, oo = lane & 3;
        uint4 val = *(const uint4*)&Pw[row*40 + oo*8];
        *(uint4*)&AO[((size_t)((i0 + row)*256 + j))*128 + n*32 + oo*8] = val;
    }
}

// ---------------------------------------------------------------------------
// Kernel 3: out = AO(bf16) @ Wo + bo. ONE WAVE per block. (round-6 proven)
// ---------------------------------------------------------------------------
__global__ __launch_bounds__(64)
void k_out(const unsigned short* __restrict__ AO, const unsigned short* __restrict__ WOT,
           const float* __restrict__ bo, float* __restrict__ out)
{
    const int t    = threadIdx.x;
    const int l15  = t & 15, quad = t >> 4;
    const int p0   = (blockIdx.x >> 1) * 16;
    const int cb   = (blockIdx.x & 1) * 64;

    bf16x8 a[4];
    #pragma unroll
    for (int kt = 0; kt < 4; ++kt)
        a[kt] = *(const bf16x8*)(AO + (size_t)(p0 + l15)*128 + kt*32 + quad*8);

    f32x4 acc[4];
    #pragma unroll
    for (int nt = 0; nt < 4; ++nt) acc[nt] = (f32x4){0.f,0.f,0.f,0.f};
    #pragma unroll
    for (int kt = 0; kt < 4; ++kt) {
        #pragma unroll
        for (int nt = 0; nt < 4; ++nt) {
            bf16x8 b = *(const bf16x8*)(WOT + (size_t)(cb + nt*16 + l15)*128 + kt*32 + quad*8);
            acc[nt] = __builtin_amdgcn_mfma_f32_16x16x32_bf16(a[kt], b, acc[nt], 0, 0, 0);
        }
    }
    #pragma unroll
    for (int nt = 0; nt < 4; ++nt) {
        float bov = bo[cb + nt*16 + l15];
        #pragma unroll
        for (int reg = 0; reg < 4; ++reg) {
            int p = p0 + quad*4 + reg;
            out[(size_t)p*128 + cb + nt*16 + l15] = acc[nt][reg] + bov;
        }
    }
}

// ---------------------------------------------------------------------------
extern "C" void kernel_launch(void* const* d_in, const int* in_sizes, int n_in,
                              void* d_out, int out_size, void* d_ws, size_t ws_size,
                              hipStream_t stream) {
    (void)in_sizes; (void)n_in; (void)out_size; (void)ws_size;
    const float* x     = (const float*)d_in[0];
    const float* gamma = (const float*)d_in[1];
    const float* beta  = (const float*)d_in[2];
    const float* Wq    = (const float*)d_in[3];
    const float* Wk    = (const float*)d_in[4];
    const float* Wv    = (const float*)d_in[5];
    const float* Wb    = (const float*)d_in[6];
    const float* Wg    = (const float*)d_in[7];
    const float* bg    = (const float*)d_in[8];
    const float* Wo    = (const float*)d_in[9];
    const float* bo    = (const float*)d_in[10];
    float* out = (float*)d_out;

    unsigned short* WT  = (unsigned short*)d_ws;          // 5*16384 bf16
    unsigned short* WbT = WT + 5*16384;                   // 2048 bf16
    unsigned short* Qp  = WbT + 2048;                     // 8388608 bf16 each
    unsigned short* Kp  = Qp + 8388608;
    unsigned short* VTp = Kp + 8388608;
    unsigned short* Gp  = VTp + 8388608;
    float* Bp   = (float*)(Gp + 8388608);                 // 262144 f32 (swizzled)
    unsigned short* AOp = (unsigned short*)(Bp + 262144); // 8388608 bf16
    unsigned short* WOT = WT + 4*16384;

    k_prep<<<21, 256, 0, stream>>>(Wq, Wk, Wv, Wg, Wo, Wb, WT, WbT);
    k_ln_proj<<<1024, 256, 0, stream>>>(x, gamma, beta, WT, WbT, bg,
                                        Qp, Kp, VTp, Gp, Bp);
    k_attn<<<4096, 256, 0, stream>>>(Qp, Kp, VTp, Gp, Bp, AOp);
    k_out<<<8192, 64, 0, stream>>>(AOp, WOT, bo, out);
}

// Round 3
// 227.962 us; speedup vs baseline: 1.2829x; 1.2829x over previous
//
#include <hip/hip_runtime.h>
#include <hip/hip_bf16.h>
#include <math.h>

#define SCALE 0.1767766952966369f        // 1/sqrt(32)
#define LOG2E 1.4426950408889634f
#define QSCALE 0.25503487f               // SCALE * LOG2E (softmax in exp2 domain)
#define LN_EPS 1e-5f

typedef short bf16x8 __attribute__((ext_vector_type(8)));
typedef float f32x4 __attribute__((ext_vector_type(4)));

__device__ __forceinline__ unsigned short f2bf(float f) {
    __hip_bfloat16 h = __float2bfloat16(f);
    return *reinterpret_cast<unsigned short*>(&h);
}
__device__ __forceinline__ float bf2f(unsigned short u) {
    union { unsigned int u32; float f; } c;
    c.u32 = ((unsigned int)u) << 16;
    return c.f;
}
__device__ __forceinline__ unsigned int pack2(float a, float b) {
    return (unsigned int)f2bf(a) | ((unsigned int)f2bf(b) << 16);
}

// ---------------------------------------------------------------------------
// Kernel 0: weight convert+transpose to bf16. WT[m][col][k] m=q,k,v,g,o.
// Block 20: WbT[16][128] zero-padded (rows 4..15 = 0).
// ---------------------------------------------------------------------------
__global__ __launch_bounds__(256)
void k_prep(const float* __restrict__ Wq, const float* __restrict__ Wk,
            const float* __restrict__ Wv, const float* __restrict__ Wg,
            const float* __restrict__ Wo, const float* __restrict__ Wb,
            unsigned short* __restrict__ WT, unsigned short* __restrict__ WbT)
{
    if (blockIdx.x == 20) {
        int t = threadIdx.x;
        int row = t >> 4, k0 = (t & 15) * 8;
        unsigned int u[4];
        #pragma unroll
        for (int e = 0; e < 4; ++e) {
            float a = 0.f, b = 0.f;
            if (row < 4) {
                a = Wb[(k0 + 2*e    )*4 + row];
                b = Wb[(k0 + 2*e + 1)*4 + row];
            }
            u[e] = pack2(a, b);
        }
        *(uint4*)(WbT + row*128 + k0) = make_uint4(u[0], u[1], u[2], u[3]);
        return;
    }
    int idx = blockIdx.x * 256 + threadIdx.x;     // < 5120
    int m   = idx >> 10;
    int col = (idx >> 3) & 127;
    int k0  = (idx & 7) * 16;
    const float* W = (m==0) ? Wq : (m==1) ? Wk : (m==2) ? Wv : (m==3) ? Wg : Wo;
    unsigned int u[8];
    #pragma unroll
    for (int e = 0; e < 8; ++e) {
        float a = W[(k0 + 2*e    )*128 + col];
        float b = W[(k0 + 2*e + 1)*128 + col];
        u[e] = pack2(a, b);
    }
    uint4* dst = (uint4*)(WT + m*16384 + col*128 + k0);
    dst[0] = make_uint4(u[0], u[1], u[2], u[3]);
    dst[1] = make_uint4(u[4], u[5], u[6], u[7]);
}

// ---------------------------------------------------------------------------
// Kernel 1: LN + projections, GEMM-style with W staged in LDS.
// grid 1024: j = blk>>2, i0base = (blk&3)*64. 256 thr, wave w owns one
// 16-row tile ti = i0base + w*16.
// This round: Q pre-scale folds LOG2E (exp2-domain softmax); bias * LOG2E;
// gate matrix stored TRANSPOSED (GT[d][i], same layout as VT) so k_attn
// can vector-load it.
// ---------------------------------------------------------------------------
__global__ __launch_bounds__(256)
void k_ln_proj(const float* __restrict__ x, const float* __restrict__ gamma,
               const float* __restrict__ beta,
               const unsigned short* __restrict__ WT,
               const unsigned short* __restrict__ WbT,
               const float* __restrict__ bg,
               unsigned short* __restrict__ Q, unsigned short* __restrict__ K,
               unsigned short* __restrict__ VT, unsigned short* __restrict__ GT,
               float* __restrict__ BIAS)
{
    __shared__ unsigned short Wbuf[64*136];     // staged W half  (17408 B)
    __shared__ unsigned short stg[4][2176];     // per-wave epilogue staging

    const int t    = threadIdx.x;
    const int lane = t & 63, w = t >> 6;
    const int l15  = lane & 15, quad = lane >> 4;
    const int j    = blockIdx.x >> 2;
    const int ti   = (blockIdx.x & 3) * 64 + w*16;   // this wave's 16 rows
    unsigned short* sw = stg[w];

    // ---- LayerNorm in registers (rows ti+l15, column j) ----
    float v[32];
    {
        const float* xr = x + ((size_t)(ti + l15)*256 + j)*128;
        float sum = 0.f, ssq = 0.f;
        #pragma unroll
        for (int kt = 0; kt < 4; ++kt) {
            float4 f0 = *(const float4*)(xr + kt*32 + quad*8);
            float4 f1 = *(const float4*)(xr + kt*32 + quad*8 + 4);
            v[kt*8+0]=f0.x; v[kt*8+1]=f0.y; v[kt*8+2]=f0.z; v[kt*8+3]=f0.w;
            v[kt*8+4]=f1.x; v[kt*8+5]=f1.y; v[kt*8+6]=f1.z; v[kt*8+7]=f1.w;
            sum += f0.x+f0.y+f0.z+f0.w + f1.x+f1.y+f1.z+f1.w;
            ssq += f0.x*f0.x+f0.y*f0.y+f0.z*f0.z+f0.w*f0.w
                 + f1.x*f1.x+f1.y*f1.y+f1.z*f1.z+f1.w*f1.w;
        }
        sum += __shfl_xor(sum, 16); ssq += __shfl_xor(ssq, 16);
        sum += __shfl_xor(sum, 32); ssq += __shfl_xor(ssq, 32);
        float mu  = sum * (1.f/128.f);
        float var = ssq * (1.f/128.f) - mu*mu;
        float rs  = rsqrtf(var + LN_EPS);
        #pragma unroll
        for (int kt = 0; kt < 4; ++kt)
            #pragma unroll
            for (int e = 0; e < 8; ++e) {
                int c = kt*32 + quad*8 + e;
                v[kt*8+e] = (v[kt*8+e]-mu)*rs*gamma[c] + beta[c];
            }
    }
    bf16x8 afrag[4];
    #pragma unroll
    for (int kt = 0; kt < 4; ++kt)
        #pragma unroll
        for (int e = 0; e < 8; ++e)
            afrag[kt][e] = (short)f2bf(v[kt*8+e]);

    // ---- bias via MFMA with zero-padded WbT; scaled by LOG2E ----
    {
        f32x4 bacc = (f32x4){0.f,0.f,0.f,0.f};
        #pragma unroll
        for (int kt = 0; kt < 4; ++kt) {
            bf16x8 b = *(const bf16x8*)(WbT + (size_t)l15*128 + kt*32 + quad*8);
            bacc = __builtin_amdgcn_mfma_f32_16x16x32_bf16(afrag[kt], b, bacc, 0, 0, 0);
        }
        if (l15 < 4) {
            #pragma unroll
            for (int reg = 0; reg < 4; ++reg)
                BIAS[l15*65536 + ((ti >> 2) + quad)*1024 + j*4 + reg] = bacc[reg] * LOG2E;
        }
    }

    // ---- 4 projection matrices, W through LDS in 64-col halves ----
    #pragma unroll 1
    for (int mm = 0; mm < 4; ++mm) {
        f32x4 acc[8];
        #pragma unroll
        for (int nt = 0; nt < 8; ++nt) acc[nt] = (f32x4){0.f,0.f,0.f,0.f};

        #pragma unroll 1
        for (int half = 0; half < 2; ++half) {
            __syncthreads();   // Wbuf free of previous phase's readers
            #pragma unroll
            for (int r = 0; r < 4; ++r) {
                int idx = r*256 + t;               // 1024 8-short chunks
                int col = idx >> 4, kc = idx & 15;
                *(uint4*)&Wbuf[col*136 + kc*8] =
                    *(const uint4*)&WT[mm*16384 + (half*64 + col)*128 + kc*8];
            }
            __syncthreads();

            #pragma unroll
            for (int kt = 0; kt < 4; ++kt) {
                #pragma unroll
                for (int nt2 = 0; nt2 < 4; ++nt2) {
                    bf16x8 b = *(const bf16x8*)&Wbuf[(nt2*16 + l15)*136 + kt*32 + quad*8];
                    if (mm == 2)
                        acc[half*4 + nt2] = __builtin_amdgcn_mfma_f32_16x16x32_bf16(
                            b, afrag[kt], acc[half*4 + nt2], 0, 0, 0);
                    else
                        acc[half*4 + nt2] = __builtin_amdgcn_mfma_f32_16x16x32_bf16(
                            afrag[kt], b, acc[half*4 + nt2], 0, 0, 0);
                }
            }
        }

        // ---- epilogue (per-wave staging) ----
        if (mm == 2) {
            // V swapped: rows = channel cc, cols = local position l15
            #pragma unroll
            for (int nt = 0; nt < 8; ++nt)
                #pragma unroll
                for (int reg = 0; reg < 4; ++reg)
                    sw[(nt*16 + quad*4 + reg)*16 + l15] = f2bf(acc[nt][reg]);
            #pragma unroll
            for (int it = 0; it < 4; ++it) {
                int idx = it*64 + lane;
                int ch = idx >> 1, c = idx & 1;
                uint4 val = *(const uint4*)&sw[ch*16 + c*8];
                int nh = ch >> 5, d = ch & 31;
                *(uint4*)&VT[(((size_t)(nh*256 + j))*32 + d)*256 + ti + c*8] = val;
            }
        } else if (mm == 3) {
            // gate: sigmoid, staged to [ch][i_local], stored transposed like VT
            #pragma unroll
            for (int nt = 0; nt < 8; ++nt) {
                int cc = nt*16 + l15;
                float bgv = bg[cc];
                float v0 = 1.f/(1.f + __expf(-(acc[nt][0] + bgv)));
                float v1 = 1.f/(1.f + __expf(-(acc[nt][1] + bgv)));
                float v2 = 1.f/(1.f + __expf(-(acc[nt][2] + bgv)));
                float v3 = 1.f/(1.f + __expf(-(acc[nt][3] + bgv)));
                *(uint2*)&sw[cc*16 + quad*4] = make_uint2(pack2(v0, v1), pack2(v2, v3));
            }
            #pragma unroll
            for (int it = 0; it < 4; ++it) {
                int idx = it*64 + lane;
                int ch = idx >> 1, c = idx & 1;
                uint4 val = *(const uint4*)&sw[ch*16 + c*8];
                int nh = ch >> 5, d = ch & 31;
                *(uint4*)&GT[(((size_t)(nh*256 + j))*32 + d)*256 + ti + c*8] = val;
            }
        } else {
            #pragma unroll
            for (int nt = 0; nt < 8; ++nt) {
                int cc = nt*16 + l15;
                #pragma unroll
                for (int reg = 0; reg < 4; ++reg) {
                    float val = acc[nt][reg];
                    if (mm == 0) val *= QSCALE;       // SCALE * LOG2E
                    sw[(quad*4 + reg)*136 + cc] = f2bf(val);
                }
            }
            {
                int row = lane >> 2, c = lane & 3;
                unsigned short* Dst = (mm == 0) ? Q : K;
                #pragma unroll
                for (int nh = 0; nh < 4; ++nh) {
                    uint4 val = *(const uint4*)&sw[row*136 + nh*32 + c*8];
                    *(uint4*)&Dst[(((size_t)(nh*256 + j))*256 + ti + row)*32 + c*8] = val;
                }
            }
        }
    }
}

// ---------------------------------------------------------------------------
// Kernel 2: attention. EXACT round-0 structure (proven 67.5 us): grid 4096
// with bid = (n<<10)|(j<<2)|ic (panel-sharing blocks consecutive), LDS P path,
// zero barriers. Micro-changes only:
//  (a) gate loads: 2x 8B vector loads from GT[d][i], hoisted to kernel start
//      (were 8 scalar u16 loads on the epilogue critical path);
//  (b) exp2f instead of __expf (scores pre-scaled by LOG2E upstream).
// ---------------------------------------------------------------------------
__global__ __launch_bounds__(256)
void k_attn(const unsigned short* __restrict__ Q, const unsigned short* __restrict__ K,
            const unsigned short* __restrict__ VT, const unsigned short* __restrict__ GT,
            const float* __restrict__ BIAS, unsigned short* __restrict__ AO)
{
    __shared__ unsigned short P_lds[4][16*264];

    const int t    = threadIdx.x;
    const int n    = blockIdx.x >> 10;
    const int j    = (blockIdx.x >> 2) & 255;
    const int ic   = blockIdx.x & 3;
    const int lane = t & 63, w = t >> 6;
    const int l15  = lane & 15, quad = lane >> 4;
    const int i0   = ic*64 + w*16;

    const size_t nb = (size_t)(n*256 + j);
    const unsigned short* qb  = Q  + nb*8192;   // [i][d], pre-scaled
    const unsigned short* kb  = K  + nb*8192;   // [k][d]
    const unsigned short* vtb = VT + nb*8192;   // [d][k]
    const unsigned short* gtb = GT + nb*8192;   // [d][i]
    const float* biasn = BIAS + n*65536;        // [i>>2][k][i&3]
    unsigned short* Pw = P_lds[w];

    // hoisted, fully-independent gate loads
    uint2 gw0 = *(const uint2*)(gtb + (size_t)l15*256        + i0 + quad*4);
    uint2 gw1 = *(const uint2*)(gtb + (size_t)(16 + l15)*256 + i0 + quad*4);

    bf16x8 a = *(const bf16x8*)(qb + (size_t)(i0 + l15)*32 + quad*8);
    f32x4 acc[16];
    #pragma unroll
    for (int kt = 0; kt < 16; ++kt) {
        bf16x8 b = *(const bf16x8*)(kb + (size_t)(kt*16 + l15)*32 + quad*8);
        acc[kt] = __builtin_amdgcn_mfma_f32_16x16x32_bf16(a, b, (f32x4){0.f,0.f,0.f,0.f}, 0, 0, 0);
    }

    float mx[4] = {-1e30f, -1e30f, -1e30f, -1e30f};
    #pragma unroll
    for (int kt = 0; kt < 16; ++kt) {
        float4 bv = *(const float4*)&biasn[((i0 >> 2) + quad)*1024 + (kt*16 + l15)*4];
        acc[kt][0] += bv.x; acc[kt][1] += bv.y;
        acc[kt][2] += bv.z; acc[kt][3] += bv.w;
        #pragma unroll
        for (int reg = 0; reg < 4; ++reg)
            mx[reg] = fmaxf(mx[reg], acc[kt][reg]);
    }
    #pragma unroll
    for (int m = 1; m <= 8; m <<= 1) {
        #pragma unroll
        for (int reg = 0; reg < 4; ++reg)
            mx[reg] = fmaxf(mx[reg], __shfl_xor(mx[reg], m));
    }

    float sm[4] = {0.f, 0.f, 0.f, 0.f};
    #pragma unroll
    for (int kt = 0; kt < 16; ++kt) {
        #pragma unroll
        for (int reg = 0; reg < 4; ++reg) {
            float e = exp2f(acc[kt][reg] - mx[reg]);
            acc[kt][reg] = e;
            sm[reg] += e;
        }
    }
    #pragma unroll
    for (int m = 1; m <= 8; m <<= 1) {
        #pragma unroll
        for (int reg = 0; reg < 4; ++reg)
            sm[reg] += __shfl_xor(sm[reg], m);
    }
    float rinv[4];
    #pragma unroll
    for (int reg = 0; reg < 4; ++reg) rinv[reg] = 1.f / sm[reg];

    #pragma unroll
    for (int kt = 0; kt < 16; ++kt) {
        #pragma unroll
        for (int reg = 0; reg < 4; ++reg)
            Pw[(quad*4 + reg)*264 + kt*16 + l15] = f2bf(acc[kt][reg]);
    }

    f32x4 o[2];
    o[0] = (f32x4){0.f,0.f,0.f,0.f};
    o[1] = (f32x4){0.f,0.f,0.f,0.f};
    #pragma unroll
    for (int kt8 = 0; kt8 < 8; ++kt8) {
        bf16x8 pa = *(const bf16x8*)(Pw + l15*264 + kt8*32 + quad*8);
        #pragma unroll
        for (int nt = 0; nt < 2; ++nt) {
            bf16x8 vb = *(const bf16x8*)(vtb + (size_t)(nt*16 + l15)*256 + kt8*32 + quad*8);
            o[nt] = __builtin_amdgcn_mfma_f32_16x16x32_bf16(pa, vb, o[nt], 0, 0, 0);
        }
    }

    // gate + normalize -> stage -> coalesced store
    float gg[2][4] = {
        { bf2f((unsigned short)(gw0.x & 0xffff)), bf2f((unsigned short)(gw0.x >> 16)),
          bf2f((unsigned short)(gw0.y & 0xffff)), bf2f((unsigned short)(gw0.y >> 16)) },
        { bf2f((unsigned short)(gw1.x & 0xffff)), bf2f((unsigned short)(gw1.x >> 16)),
          bf2f((unsigned short)(gw1.y & 0xffff)), bf2f((unsigned short)(gw1.y >> 16)) } };
    #pragma unroll
    for (int nt = 0; nt < 2; ++nt) {
        #pragma unroll
        for (int reg = 0; reg < 4; ++reg) {
            float res = o[nt][reg] * rinv[reg] * gg[nt][reg];
            Pw[(quad*4 + reg)*40 + nt*16 + l15] = f2bf(res);
        }
    }
    {
        int row = lane >> 2, oo = lane & 3;
        uint4 val = *(const uint4*)&Pw[row*40 + oo*8];
        *(uint4*)&AO[((size_t)((i0 + row)*256 + j))*128 + n*32 + oo*8] = val;
    }
}

// ---------------------------------------------------------------------------
// Kernel 3: out = AO(bf16) @ Wo + bo. REWRITTEN: 1024 blocks x 256 thr,
// Wo staged once per block in LDS (34816 B), wave w owns one 16-row x
// 128-col tile (32 MFMAs). Was 8192 one-wave blocks each re-reading Wo.
// ---------------------------------------------------------------------------
__global__ __launch_bounds__(256)
void k_out(const unsigned short* __restrict__ AO, const unsigned short* __restrict__ WOT,
           const float* __restrict__ bo, float* __restrict__ out)
{
    __shared__ unsigned short WB[128*136];   // 34816 B

    const int t    = threadIdx.x;
    const int lane = t & 63, w = t >> 6;
    const int l15  = lane & 15, quad = lane >> 4;
    const int p0   = (blockIdx.x*4 + w) * 16;

    #pragma unroll
    for (int r = 0; r < 8; ++r) {
        int idx = r*256 + t;                 // 2048 chunks of 8 shorts
        int col = idx >> 4, kc = idx & 15;
        *(uint4*)&WB[col*136 + kc*8] = *(const uint4*)&WOT[col*128 + kc*8];
    }

    bf16x8 a[4];
    #pragma unroll
    for (int kt = 0; kt < 4; ++kt)
        a[kt] = *(const bf16x8*)(AO + (size_t)(p0 + l15)*128 + kt*32 + quad*8);

    __syncthreads();

    f32x4 acc[8];
    #pragma unroll
    for (int nt = 0; nt < 8; ++nt) acc[nt] = (f32x4){0.f,0.f,0.f,0.f};
    #pragma unroll
    for (int kt = 0; kt < 4; ++kt) {
        #pragma unroll
        for (int nt = 0; nt < 8; ++nt) {
            bf16x8 b = *(const bf16x8*)&WB[(nt*16 + l15)*136 + kt*32 + quad*8];
            acc[nt] = __builtin_amdgcn_mfma_f32_16x16x32_bf16(a[kt], b, acc[nt], 0, 0, 0);
        }
    }
    #pragma unroll
    for (int nt = 0; nt < 8; ++nt) {
        float bov = bo[nt*16 + l15];
        #pragma unroll
        for (int reg = 0; reg < 4; ++reg) {
            int p = p0 + quad*4 + reg;
            out[(size_t)p*128 + nt*16 + l15] = acc[nt][reg] + bov;
        }
    }
}

// ---------------------------------------------------------------------------
extern "C" void kernel_launch(void* const* d_in, const int* in_sizes, int n_in,
                              void* d_out, int out_size, void* d_ws, size_t ws_size,
                              hipStream_t stream) {
    (void)in_sizes; (void)n_in; (void)out_size; (void)ws_size;
    const float* x     = (const float*)d_in[0];
    const float* gamma = (const float*)d_in[1];
    const float* beta  = (const float*)d_in[2];
    const float* Wq    = (const float*)d_in[3];
    const float* Wk    = (const float*)d_in[4];
    const float* Wv    = (const float*)d_in[5];
    const float* Wb    = (const float*)d_in[6];
    const float* Wg    = (const float*)d_in[7];
    const float* bg    = (const float*)d_in[8];
    const float* Wo    = (const float*)d_in[9];
    const float* bo    = (const float*)d_in[10];
    float* out = (float*)d_out;

    unsigned short* WT  = (unsigned short*)d_ws;          // 5*16384 bf16
    unsigned short* WbT = WT + 5*16384;                   // 2048 bf16
    unsigned short* Qp  = WbT + 2048;                     // 8388608 bf16 each
    unsigned short* Kp  = Qp + 8388608;
    unsigned short* VTp = Kp + 8388608;
    unsigned short* GTp = VTp + 8388608;
    float* Bp   = (float*)(GTp + 8388608);                // 262144 f32 (swizzled)
    unsigned short* AOp = (unsigned short*)(Bp + 262144); // 8388608 bf16
    unsigned short* WOT = WT + 4*16384;

    k_prep<<<21, 256, 0, stream>>>(Wq, Wk, Wv, Wg, Wo, Wb, WT, WbT);
    k_ln_proj<<<1024, 256, 0, stream>>>(x, gamma, beta, WT, WbT, bg,
                                        Qp, Kp, VTp, GTp, Bp);
    k_attn<<<4096, 256, 0, stream>>>(Qp, Kp, VTp, GTp, Bp, AOp);
    k_out<<<1024, 256, 0, stream>>>(AOp, WOT, bo, out);
}

// Round 4
// 209.034 us; speedup vs baseline: 1.3991x; 1.0905x over previous
//
#include <hip/hip_runtime.h>
#include <hip/hip_bf16.h>
#include <math.h>

#define SCALE 0.1767766952966369f        // 1/sqrt(32)
#define LN_EPS 1e-5f

typedef short bf16x8 __attribute__((ext_vector_type(8)));
typedef float f32x4 __attribute__((ext_vector_type(4)));

__device__ __forceinline__ unsigned short f2bf(float f) {
    __hip_bfloat16 h = __float2bfloat16(f);
    return *reinterpret_cast<unsigned short*>(&h);
}
__device__ __forceinline__ float bf2f(unsigned short u) {
    union { unsigned int u32; float f; } c;
    c.u32 = ((unsigned int)u) << 16;
    return c.f;
}
__device__ __forceinline__ unsigned int pack2(float a, float b) {
    return (unsigned int)f2bf(a) | ((unsigned int)f2bf(b) << 16);
}

// ---------------------------------------------------------------------------
// Kernel 0: weight convert+transpose to bf16. WT[m][col][k] m=q,k,v,g,o.
// Block 20: WbT[16][128] zero-padded (rows 4..15 = 0).  (round-0 exact)
// ---------------------------------------------------------------------------
__global__ __launch_bounds__(256)
void k_prep(const float* __restrict__ Wq, const float* __restrict__ Wk,
            const float* __restrict__ Wv, const float* __restrict__ Wg,
            const float* __restrict__ Wo, const float* __restrict__ Wb,
            unsigned short* __restrict__ WT, unsigned short* __restrict__ WbT)
{
    if (blockIdx.x == 20) {
        int t = threadIdx.x;
        int row = t >> 4, k0 = (t & 15) * 8;
        unsigned int u[4];
        #pragma unroll
        for (int e = 0; e < 4; ++e) {
            float a = 0.f, b = 0.f;
            if (row < 4) {
                a = Wb[(k0 + 2*e    )*4 + row];
                b = Wb[(k0 + 2*e + 1)*4 + row];
            }
            u[e] = pack2(a, b);
        }
        *(uint4*)(WbT + row*128 + k0) = make_uint4(u[0], u[1], u[2], u[3]);
        return;
    }
    int idx = blockIdx.x * 256 + threadIdx.x;     // < 5120
    int m   = idx >> 10;
    int col = (idx >> 3) & 127;
    int k0  = (idx & 7) * 16;
    const float* W = (m==0) ? Wq : (m==1) ? Wk : (m==2) ? Wv : (m==3) ? Wg : Wo;
    unsigned int u[8];
    #pragma unroll
    for (int e = 0; e < 8; ++e) {
        float a = W[(k0 + 2*e    )*128 + col];
        float b = W[(k0 + 2*e + 1)*128 + col];
        u[e] = pack2(a, b);
    }
    uint4* dst = (uint4*)(WT + m*16384 + col*128 + k0);
    dst[0] = make_uint4(u[0], u[1], u[2], u[3]);
    dst[1] = make_uint4(u[4], u[5], u[6], u[7]);
}

// ---------------------------------------------------------------------------
// Kernel 1: LN + projections, GEMM-style with W staged in LDS.
// ROUND-0 EXACT (proven as part of the 224.2 us baseline).
// ---------------------------------------------------------------------------
__global__ __launch_bounds__(256)
void k_ln_proj(const float* __restrict__ x, const float* __restrict__ gamma,
               const float* __restrict__ beta,
               const unsigned short* __restrict__ WT,
               const unsigned short* __restrict__ WbT,
               const float* __restrict__ bg,
               unsigned short* __restrict__ Q, unsigned short* __restrict__ K,
               unsigned short* __restrict__ VT, unsigned short* __restrict__ G,
               float* __restrict__ BIAS)
{
    __shared__ unsigned short Wbuf[64*136];     // staged W half  (17408 B)
    __shared__ unsigned short stg[4][2176];     // per-wave epilogue staging

    const int t    = threadIdx.x;
    const int lane = t & 63, w = t >> 6;
    const int l15  = lane & 15, quad = lane >> 4;
    const int j    = blockIdx.x >> 2;
    const int ti   = (blockIdx.x & 3) * 64 + w*16;   // this wave's 16 rows
    unsigned short* sw = stg[w];

    // ---- LayerNorm in registers (rows ti+l15, column j) ----
    float v[32];
    {
        const float* xr = x + ((size_t)(ti + l15)*256 + j)*128;
        float sum = 0.f, ssq = 0.f;
        #pragma unroll
        for (int kt = 0; kt < 4; ++kt) {
            float4 f0 = *(const float4*)(xr + kt*32 + quad*8);
            float4 f1 = *(const float4*)(xr + kt*32 + quad*8 + 4);
            v[kt*8+0]=f0.x; v[kt*8+1]=f0.y; v[kt*8+2]=f0.z; v[kt*8+3]=f0.w;
            v[kt*8+4]=f1.x; v[kt*8+5]=f1.y; v[kt*8+6]=f1.z; v[kt*8+7]=f1.w;
            sum += f0.x+f0.y+f0.z+f0.w + f1.x+f1.y+f1.z+f1.w;
            ssq += f0.x*f0.x+f0.y*f0.y+f0.z*f0.z+f0.w*f0.w
                 + f1.x*f1.x+f1.y*f1.y+f1.z*f1.z+f1.w*f1.w;
        }
        sum += __shfl_xor(sum, 16); ssq += __shfl_xor(ssq, 16);
        sum += __shfl_xor(sum, 32); ssq += __shfl_xor(ssq, 32);
        float mu  = sum * (1.f/128.f);
        float var = ssq * (1.f/128.f) - mu*mu;
        float rs  = rsqrtf(var + LN_EPS);
        #pragma unroll
        for (int kt = 0; kt < 4; ++kt)
            #pragma unroll
            for (int e = 0; e < 8; ++e) {
                int c = kt*32 + quad*8 + e;
                v[kt*8+e] = (v[kt*8+e]-mu)*rs*gamma[c] + beta[c];
            }
    }
    bf16x8 afrag[4];
    #pragma unroll
    for (int kt = 0; kt < 4; ++kt)
        #pragma unroll
        for (int e = 0; e < 8; ++e)
            afrag[kt][e] = (short)f2bf(v[kt*8+e]);

    // ---- bias via MFMA with zero-padded WbT (global, tiny) ----
    {
        f32x4 bacc = (f32x4){0.f,0.f,0.f,0.f};
        #pragma unroll
        for (int kt = 0; kt < 4; ++kt) {
            bf16x8 b = *(const bf16x8*)(WbT + (size_t)l15*128 + kt*32 + quad*8);
            bacc = __builtin_amdgcn_mfma_f32_16x16x32_bf16(afrag[kt], b, bacc, 0, 0, 0);
        }
        if (l15 < 4) {
            #pragma unroll
            for (int reg = 0; reg < 4; ++reg)
                BIAS[l15*65536 + ((ti >> 2) + quad)*1024 + j*4 + reg] = bacc[reg];
        }
    }

    // ---- 4 projection matrices, W through LDS in 64-col halves ----
    #pragma unroll 1
    for (int mm = 0; mm < 4; ++mm) {
        f32x4 acc[8];
        #pragma unroll
        for (int nt = 0; nt < 8; ++nt) acc[nt] = (f32x4){0.f,0.f,0.f,0.f};

        #pragma unroll 1
        for (int half = 0; half < 2; ++half) {
            __syncthreads();   // Wbuf free of previous phase's readers
            #pragma unroll
            for (int r = 0; r < 4; ++r) {
                int idx = r*256 + t;               // 1024 8-short chunks
                int col = idx >> 4, kc = idx & 15;
                *(uint4*)&Wbuf[col*136 + kc*8] =
                    *(const uint4*)&WT[mm*16384 + (half*64 + col)*128 + kc*8];
            }
            __syncthreads();

            #pragma unroll
            for (int kt = 0; kt < 4; ++kt) {
                #pragma unroll
                for (int nt2 = 0; nt2 < 4; ++nt2) {
                    bf16x8 b = *(const bf16x8*)&Wbuf[(nt2*16 + l15)*136 + kt*32 + quad*8];
                    if (mm == 2)
                        acc[half*4 + nt2] = __builtin_amdgcn_mfma_f32_16x16x32_bf16(
                            b, afrag[kt], acc[half*4 + nt2], 0, 0, 0);
                    else
                        acc[half*4 + nt2] = __builtin_amdgcn_mfma_f32_16x16x32_bf16(
                            afrag[kt], b, acc[half*4 + nt2], 0, 0, 0);
                }
            }
        }

        // ---- epilogue (per-wave staging, round-0 pattern) ----
        if (mm == 2) {
            // V swapped: rows = channel cc, cols = local position l15
            #pragma unroll
            for (int nt = 0; nt < 8; ++nt)
                #pragma unroll
                for (int reg = 0; reg < 4; ++reg)
                    sw[(nt*16 + quad*4 + reg)*16 + l15] = f2bf(acc[nt][reg]);
            #pragma unroll
            for (int it = 0; it < 4; ++it) {
                int idx = it*64 + lane;
                int ch = idx >> 1, c = idx & 1;
                uint4 val = *(const uint4*)&sw[ch*16 + c*8];
                int nh = ch >> 5, d = ch & 31;
                *(uint4*)&VT[(((size_t)(nh*256 + j))*32 + d)*256 + ti + c*8] = val;
            }
        } else {
            #pragma unroll
            for (int nt = 0; nt < 8; ++nt) {
                int cc = nt*16 + l15;
                float bgv = (mm == 3) ? bg[cc] : 0.f;
                #pragma unroll
                for (int reg = 0; reg < 4; ++reg) {
                    float val = acc[nt][reg];
                    if (mm == 0)      val *= SCALE;
                    else if (mm == 3) val = 1.f/(1.f + __expf(-(val + bgv)));
                    sw[(quad*4 + reg)*136 + cc] = f2bf(val);
                }
            }
            {
                int row = lane >> 2, c = lane & 3;
                unsigned short* Dst = (mm == 0) ? Q : (mm == 1) ? K : G;
                #pragma unroll
                for (int nh = 0; nh < 4; ++nh) {
                    uint4 val = *(const uint4*)&sw[row*136 + nh*32 + c*8];
                    *(uint4*)&Dst[(((size_t)(nh*256 + j))*256 + ti + row)*32 + c*8] = val;
                }
            }
        }
    }
}

// ---------------------------------------------------------------------------
// Kernel 2: attention. ROUND-0 EXACT (proven 67.5 us): grid 4096 (n, j, ic),
// wave w owns ONE 16-row tile, LDS P path, zero barriers.
// ---------------------------------------------------------------------------
__global__ __launch_bounds__(256)
void k_attn(const unsigned short* __restrict__ Q, const unsigned short* __restrict__ K,
            const unsigned short* __restrict__ VT, const unsigned short* __restrict__ G,
            const float* __restrict__ BIAS, unsigned short* __restrict__ AO)
{
    __shared__ unsigned short P_lds[4][16*264];

    const int t    = threadIdx.x;
    const int n    = blockIdx.x >> 10;
    const int j    = (blockIdx.x >> 2) & 255;
    const int ic   = blockIdx.x & 3;
    const int lane = t & 63, w = t >> 6;
    const int l15  = lane & 15, quad = lane >> 4;
    const int i0   = ic*64 + w*16;

    const size_t nb = (size_t)(n*256 + j);
    const unsigned short* qb  = Q  + nb*8192;   // [i][d], pre-scaled
    const unsigned short* kb  = K  + nb*8192;   // [k][d]
    const unsigned short* vtb = VT + nb*8192;   // [d][k]
    const unsigned short* gb  = G  + nb*8192;   // [i][d]
    const float* biasn = BIAS + n*65536;        // [i>>2][k][i&3]
    unsigned short* Pw = P_lds[w];

    bf16x8 a = *(const bf16x8*)(qb + (size_t)(i0 + l15)*32 + quad*8);
    f32x4 acc[16];
    #pragma unroll
    for (int kt = 0; kt < 16; ++kt) {
        bf16x8 b = *(const bf16x8*)(kb + (size_t)(kt*16 + l15)*32 + quad*8);
        acc[kt] = __builtin_amdgcn_mfma_f32_16x16x32_bf16(a, b, (f32x4){0.f,0.f,0.f,0.f}, 0, 0, 0);
    }

    float mx[4] = {-1e30f, -1e30f, -1e30f, -1e30f};
    #pragma unroll
    for (int kt = 0; kt < 16; ++kt) {
        float4 bv = *(const float4*)&biasn[((i0 >> 2) + quad)*1024 + (kt*16 + l15)*4];
        acc[kt][0] += bv.x; acc[kt][1] += bv.y;
        acc[kt][2] += bv.z; acc[kt][3] += bv.w;
        #pragma unroll
        for (int reg = 0; reg < 4; ++reg)
            mx[reg] = fmaxf(mx[reg], acc[kt][reg]);
    }
    #pragma unroll
    for (int m = 1; m <= 8; m <<= 1) {
        #pragma unroll
        for (int reg = 0; reg < 4; ++reg)
            mx[reg] = fmaxf(mx[reg], __shfl_xor(mx[reg], m));
    }

    float sm[4] = {0.f, 0.f, 0.f, 0.f};
    #pragma unroll
    for (int kt = 0; kt < 16; ++kt) {
        #pragma unroll
        for (int reg = 0; reg < 4; ++reg) {
            float e = __expf(acc[kt][reg] - mx[reg]);
            acc[kt][reg] = e;
            sm[reg] += e;
        }
    }
    #pragma unroll
    for (int m = 1; m <= 8; m <<= 1) {
        #pragma unroll
        for (int reg = 0; reg < 4; ++reg)
            sm[reg] += __shfl_xor(sm[reg], m);
    }
    float rinv[4];
    #pragma unroll
    for (int reg = 0; reg < 4; ++reg) rinv[reg] = 1.f / sm[reg];

    #pragma unroll
    for (int kt = 0; kt < 16; ++kt) {
        #pragma unroll
        for (int reg = 0; reg < 4; ++reg)
            Pw[(quad*4 + reg)*264 + kt*16 + l15] = f2bf(acc[kt][reg]);
    }

    f32x4 o[2];
    o[0] = (f32x4){0.f,0.f,0.f,0.f};
    o[1] = (f32x4){0.f,0.f,0.f,0.f};
    #pragma unroll
    for (int kt8 = 0; kt8 < 8; ++kt8) {
        bf16x8 pa = *(const bf16x8*)(Pw + l15*264 + kt8*32 + quad*8);
        #pragma unroll
        for (int nt = 0; nt < 2; ++nt) {
            bf16x8 vb = *(const bf16x8*)(vtb + (size_t)(nt*16 + l15)*256 + kt8*32 + quad*8);
            o[nt] = __builtin_amdgcn_mfma_f32_16x16x32_bf16(pa, vb, o[nt], 0, 0, 0);
        }
    }

    // gate + normalize -> stage -> coalesced store
    #pragma unroll
    for (int nt = 0; nt < 2; ++nt) {
        #pragma unroll
        for (int reg = 0; reg < 4; ++reg) {
            int i = i0 + quad*4 + reg;
            float g = bf2f(gb[(size_t)i*32 + nt*16 + l15]);
            float res = o[nt][reg] * rinv[reg] * g;
            Pw[(quad*4 + reg)*40 + nt*16 + l15] = f2bf(res);
        }
    }
    {
        int row = lane >> 2, oo = lane & 3;
        uint4 val = *(const uint4*)&Pw[row*40 + oo*8];
        *(uint4*)&AO[((size_t)((i0 + row)*256 + j))*128 + n*32 + oo*8] = val;
    }
}

// ---------------------------------------------------------------------------
// Kernel 3: out = AO(bf16) @ Wo + bo. KEPT from round 3 (the one proven win):
// 1024 blocks x 256 thr, Wo staged once per block in LDS (34816 B), wave w
// owns one 16-row x 128-col tile (32 MFMAs).
// ---------------------------------------------------------------------------
__global__ __launch_bounds__(256)
void k_out(const unsigned short* __restrict__ AO, const unsigned short* __restrict__ WOT,
           const float* __restrict__ bo, float* __restrict__ out)
{
    __shared__ unsigned short WB[128*136];   // 34816 B

    const int t    = threadIdx.x;
    const int lane = t & 63, w = t >> 6;
    const int l15  = lane & 15, quad = lane >> 4;
    const int p0   = (blockIdx.x*4 + w) * 16;

    #pragma unroll
    for (int r = 0; r < 8; ++r) {
        int idx = r*256 + t;                 // 2048 chunks of 8 shorts
        int col = idx >> 4, kc = idx & 15;
        *(uint4*)&WB[col*136 + kc*8] = *(const uint4*)&WOT[col*128 + kc*8];
    }

    bf16x8 a[4];
    #pragma unroll
    for (int kt = 0; kt < 4; ++kt)
        a[kt] = *(const bf16x8*)(AO + (size_t)(p0 + l15)*128 + kt*32 + quad*8);

    __syncthreads();

    f32x4 acc[8];
    #pragma unroll
    for (int nt = 0; nt < 8; ++nt) acc[nt] = (f32x4){0.f,0.f,0.f,0.f};
    #pragma unroll
    for (int kt = 0; kt < 4; ++kt) {
        #pragma unroll
        for (int nt = 0; nt < 8; ++nt) {
            bf16x8 b = *(const bf16x8*)&WB[(nt*16 + l15)*136 + kt*32 + quad*8];
            acc[nt] = __builtin_amdgcn_mfma_f32_16x16x32_bf16(a[kt], b, acc[nt], 0, 0, 0);
        }
    }
    #pragma unroll
    for (int nt = 0; nt < 8; ++nt) {
        float bov = bo[nt*16 + l15];
        #pragma unroll
        for (int reg = 0; reg < 4; ++reg) {
            int p = p0 + quad*4 + reg;
            out[(size_t)p*128 + nt*16 + l15] = acc[nt][reg] + bov;
        }
    }
}

// ---------------------------------------------------------------------------
extern "C" void kernel_launch(void* const* d_in, const int* in_sizes, int n_in,
                              void* d_out, int out_size, void* d_ws, size_t ws_size,
                              hipStream_t stream) {
    (void)in_sizes; (void)n_in; (void)out_size; (void)ws_size;
    const float* x     = (const float*)d_in[0];
    const float* gamma = (const float*)d_in[1];
    const float* beta  = (const float*)d_in[2];
    const float* Wq    = (const float*)d_in[3];
    const float* Wk    = (const float*)d_in[4];
    const float* Wv    = (const float*)d_in[5];
    const float* Wb    = (const float*)d_in[6];
    const float* Wg    = (const float*)d_in[7];
    const float* bg    = (const float*)d_in[8];
    const float* Wo    = (const float*)d_in[9];
    const float* bo    = (const float*)d_in[10];
    float* out = (float*)d_out;

    unsigned short* WT  = (unsigned short*)d_ws;          // 5*16384 bf16
    unsigned short* WbT = WT + 5*16384;                   // 2048 bf16
    unsigned short* Qp  = WbT + 2048;                     // 8388608 bf16 each
    unsigned short* Kp  = Qp + 8388608;
    unsigned short* VTp = Kp + 8388608;
    unsigned short* Gp  = VTp + 8388608;
    float* Bp   = (float*)(Gp + 8388608);                 // 262144 f32 (swizzled)
    unsigned short* AOp = (unsigned short*)(Bp + 262144); // 8388608 bf16
    unsigned short* WOT = WT + 4*16384;

    k_prep<<<21, 256, 0, stream>>>(Wq, Wk, Wv, Wg, Wo, Wb, WT, WbT);
    k_ln_proj<<<1024, 256, 0, stream>>>(x, gamma, beta, WT, WbT, bg,
                                        Qp, Kp, VTp, Gp, Bp);
    k_attn<<<4096, 256, 0, stream>>>(Qp, Kp, VTp, Gp, Bp, AOp);
    k_out<<<1024, 256, 0, stream>>>(AOp, WOT, bo, out);
}